// Round 12
// baseline (3821.725 us; speedup 1.0000x reference)
//
#include <hip/hip_runtime.h>
#include <stdint.h>

#define C 128

// ---------------- helpers ----------------

__global__ void kz(float* a, long n){
  long i = (long)blockIdx.x * 256 + threadIdx.x;
  if (i < n) a[i] = 0.f;
}

__global__ void kinit(const float* __restrict__ x, float* cur, float* acc, long n){
  long i = (long)blockIdx.x * 256 + threadIdx.x;
  if (i < n){ float v = x[i]; cur[i] = v; acc[i] = v; }
}

__global__ void kdeg(const int* __restrict__ row, const float* __restrict__ ew,
                     float* deg, int E){
  int e = blockIdx.x * 256 + threadIdx.x;
  if (e < E) atomicAdd(&deg[row[e]], ew[e]);
}

__global__ void kdinv(const float* __restrict__ deg, float* dinv, int N){
  int i = blockIdx.x * 256 + threadIdx.x;
  if (i < N){ float d = deg[i]; dinv[i] = d > 0.f ? 1.0f / sqrtf(d) : 0.f; }
}

__global__ void kcoef(const int* __restrict__ row, const int* __restrict__ col,
                      const float* __restrict__ ew, const float* __restrict__ dinv,
                      float* coef, int E){
  int e = blockIdx.x * 256 + threadIdx.x;
  if (e < E) coef[e] = dinv[row[e]] * dinv[col[e]] * ew[e];
}

// ---------------- projection + normalize (torch convention: y = x @ W.T + b) ----------------
__global__ __launch_bounds__(128) void kproj(const float* __restrict__ x,
      const float* __restrict__ Wq, const float* __restrict__ Wqb,
      const float* __restrict__ Wk, const float* __restrict__ Wkb,
      float* __restrict__ qs, float* __restrict__ ks){
  int n = blockIdx.x, t = threadIdx.x;
  __shared__ float xs[C];
  __shared__ float red[C];
  xs[t] = x[(size_t)n * C + t];
  __syncthreads();
  float q = Wqb[t], k = Wkb[t];
  for (int c = 0; c < C; c++){
    q += xs[c] * Wq[(size_t)t * C + c];
    k += xs[c] * Wk[(size_t)t * C + c];
  }
  red[t] = q * q; __syncthreads();
  for (int o = 64; o; o >>= 1){ if (t < o) red[t] += red[t + o]; __syncthreads(); }
  float qn = sqrtf(red[0]); __syncthreads();
  red[t] = k * k; __syncthreads();
  for (int o = 64; o; o >>= 1){ if (t < o) red[t] += red[t + o]; __syncthreads(); }
  float kn = sqrtf(red[0]);
  qs[(size_t)n * C + t] = q / qn;
  ks[(size_t)n * C + t] = k / kn;
}

// per-graph channel sum (ksum / vsum): one block per graph
__global__ __launch_bounds__(128) void ksumk(const float* __restrict__ v,
                                             float* __restrict__ outv, int PG){
  int b = blockIdx.x, t = threadIdx.x;
  const float* p = v + (size_t)b * PG * C + t;
  float s = 0.f;
  for (int n = 0; n < PG; n++) s += p[(size_t)n * C];
  outv[b * C + t] = s;
}

// denom[n] = qs[n]·ksum[b] + n_nodes[b]
__global__ __launch_bounds__(128) void kden(const float* __restrict__ qs,
      const float* __restrict__ ksum, const int* __restrict__ nn,
      float* __restrict__ denom, int PG){
  int n = blockIdx.x, t = threadIdx.x;
  int b = n / PG;
  __shared__ float red[C];
  red[t] = qs[(size_t)n * C + t] * ksum[b * C + t];
  __syncthreads();
  for (int o = 64; o; o >>= 1){ if (t < o) red[t] += red[t + o]; __syncthreads(); }
  if (t == 0) denom[n] = red[0] + (float)nn[b];
}

// M[b][i][j] = sum_{n in graph b} ks[n][i] * cur[n][j]
__global__ __launch_bounds__(128) void kM(const float* __restrict__ ks,
      const float* __restrict__ cur, float* __restrict__ M, int PG){
  int b = blockIdx.x, i = blockIdx.y, j = threadIdx.x;
  const float* kp = ks + (size_t)b * PG * C + i;
  const float* cp = cur + (size_t)b * PG * C + j;
  float s = 0.f;
  for (int n = 0; n < PG; n++) s += kp[(size_t)n * C] * cp[(size_t)n * C];
  M[((size_t)b * C + i) * C + j] = s;
}

// gcn[row[e]][c] += coef[e] * cur[col[e]][c]
__global__ void kscat(const int* __restrict__ row, const int* __restrict__ col,
                      const float* __restrict__ coef, const float* __restrict__ cur,
                      float* __restrict__ gcn, long EC){
  long idx = (long)blockIdx.x * 256 + threadIdx.x;
  if (idx >= EC) return;
  int e = (int)(idx >> 7);
  int c = (int)(idx & 127);
  atomicAdd(&gcn[(size_t)row[e] * C + c], coef[e] * cur[(size_t)col[e] * C + c]);
}

// attn = (qs[n]·M[b][:,d] + vsum[b][d]) / denom[n]; cur = 0.5*(gcn+attn); acc += cur
__global__ __launch_bounds__(128) void kcomb(const float* __restrict__ qs,
      const float* __restrict__ M, const float* __restrict__ vsum,
      const float* __restrict__ denom, const float* __restrict__ gcn,
      float* __restrict__ cur, float* __restrict__ acc, int PG){
  int n = blockIdx.x, d = threadIdx.x;
  int b = n / PG;
  __shared__ float qrow[C];
  qrow[d] = qs[(size_t)n * C + d];
  __syncthreads();
  const float* Mb = M + (size_t)b * C * C;
  float num = vsum[b * C + d];
  for (int i = 0; i < C; i++) num += qrow[i] * Mb[(size_t)i * C + d];
  float attn = num / denom[n];
  float nc = 0.5f * (gcn[(size_t)n * C + d] + attn);   // BETA = 0.5
  cur[(size_t)n * C + d] = nc;
  acc[(size_t)n * C + d] += nc;
}

// out[n][o] = acc[n] @ Wo.T + Wob[o]  -- FP32 OUTPUT (reference returns float32!)
__global__ __launch_bounds__(128) void kfin(const float* __restrict__ acc,
      const float* __restrict__ Wo, const float* __restrict__ Wob,
      float* __restrict__ out){
  int n = blockIdx.x, o = threadIdx.x;
  __shared__ float ar[C];
  ar[o] = acc[(size_t)n * C + o];
  __syncthreads();
  float s = Wob[o];
  for (int c = 0; c < C; c++) s += ar[c] * Wo[(size_t)o * C + c];
  out[(size_t)n * C + o] = s;
}

// ================= host =================

extern "C" void kernel_launch(void* const* d_in, const int* in_sizes, int n_in,
                              void* d_out, int out_size, void* d_ws, size_t ws_size,
                              hipStream_t stream){
  const float* x    = (const float*)d_in[0];
  const int*   eidx = (const int*)d_in[1];
  const float* ew   = (const float*)d_in[2];
  const int*   nn   = (const int*)d_in[3];
  const float* Wq   = (const float*)d_in[4];   // dict order, torch convention
  const float* Wqb  = (const float*)d_in[5];
  const float* Wk   = (const float*)d_in[6];
  const float* Wkb  = (const float*)d_in[7];
  const float* Wo   = (const float*)d_in[8];
  const float* Wob  = (const float*)d_in[9];
  float* out = (float*)d_out;                  // fp32 output — the R2-R11 bug was bf16 here

  int N = in_sizes[0] / C;
  int E = in_sizes[2];
  int B = in_sizes[3];
  int PG = N / B;
  const int* row = eidx;        // edge_index[0]
  const int* col = eidx + E;    // edge_index[1]

  char* p = (char*)d_ws;
  auto alloc = [&](size_t bytes) -> void* {
    void* r = (void*)p; p += (bytes + 255) & ~(size_t)255; return r;
  };
  float* qs   = (float*)alloc((size_t)N * C * 4);
  float* ks   = (float*)alloc((size_t)N * C * 4);
  float* cur  = (float*)alloc((size_t)N * C * 4);
  float* acc  = (float*)alloc((size_t)N * C * 4);
  float* gcn  = (float*)alloc((size_t)N * C * 4);
  float* M    = (float*)alloc((size_t)B * C * C * 4);
  float* deg  = (float*)alloc((size_t)N * 4);
  float* dinv = (float*)alloc((size_t)N * 4);
  float* coef = (float*)alloc((size_t)E * 4);
  float* ksum = (float*)alloc((size_t)B * C * 4);
  float* vsum = (float*)alloc((size_t)B * C * 4);
  float* denom= (float*)alloc((size_t)N * 4);

  long NC = (long)N * C;
  long EC = (long)E * C;
  dim3 b256(256), b128(128);

  // graph-invariant prep
  kz<<<dim3((N + 255) / 256), b256, 0, stream>>>(deg, N);
  kdeg<<<dim3((E + 255) / 256), b256, 0, stream>>>(row, ew, deg, E);
  kdinv<<<dim3((N + 255) / 256), b256, 0, stream>>>(deg, dinv, N);
  kcoef<<<dim3((E + 255) / 256), b256, 0, stream>>>(row, col, ew, dinv, coef, E);
  kinit<<<dim3((int)((NC + 255) / 256)), b256, 0, stream>>>(x, cur, acc, NC);
  kproj<<<dim3(N), b128, 0, stream>>>(x, Wq, Wqb, Wk, Wkb, qs, ks);
  ksumk<<<dim3(B), b128, 0, stream>>>(ks, ksum, PG);
  kden<<<dim3(N), b128, 0, stream>>>(qs, ksum, nn, denom, PG);

  // 4 propagation iterations
  for (int it = 0; it < 4; it++){
    ksumk<<<dim3(B), b128, 0, stream>>>(cur, vsum, PG);
    kM<<<dim3(B, C), b128, 0, stream>>>(ks, cur, M, PG);
    kz<<<dim3((int)((NC + 255) / 256)), b256, 0, stream>>>(gcn, NC);
    kscat<<<dim3((int)((EC + 255) / 256)), b256, 0, stream>>>(row, col, coef, cur, gcn, EC);
    kcomb<<<dim3(N), b128, 0, stream>>>(qs, M, vsum, denom, gcn, cur, acc, PG);
  }

  kfin<<<dim3(N), b128, 0, stream>>>(acc, Wo, Wob, out);
}

// Round 13
// 816.423 us; speedup vs baseline: 4.6811x; 4.6811x over previous
//
#include <hip/hip_runtime.h>
#include <stdint.h>

#define C 128

typedef __attribute__((ext_vector_type(8))) short bfrag;   // 8 x bf16 (4 VGPRs)
typedef __attribute__((ext_vector_type(4))) float ffrag;   // 4 x f32 accum

__device__ __forceinline__ unsigned short f2bf(float f){
  union { float f; unsigned int i; } v; v.f = f;
  unsigned int x = v.i;
  unsigned int r = x + 0x7fffu + ((x >> 16) & 1u);   // round-to-nearest-even
  return (unsigned short)(r >> 16);
}
__device__ __forceinline__ float bf2f(unsigned short u){
  union { unsigned int i; float f; } v; v.i = ((unsigned int)u) << 16; return v.f;
}

// ---------------- misc small kernels ----------------

__global__ void k_zero(float* a, int* b, int n){
  int i = blockIdx.x * 256 + threadIdx.x;
  if (i < n){ if (a) a[i] = 0.f; if (b) b[i] = 0; }
}

__global__ void k_cast(const float* __restrict__ src, unsigned short* __restrict__ dst, int n){
  int i = blockIdx.x * 256 + threadIdx.x;
  if (i < n) dst[i] = f2bf(src[i]);
}

__global__ void k_deg(const int* __restrict__ row, const float* __restrict__ w,
                      float* deg, int* cnt, int E){
  int e = blockIdx.x * 256 + threadIdx.x;
  if (e < E){
    int r = row[e];
    atomicAdd(&deg[r], w[e]);
    atomicAdd(&cnt[r], 1);
  }
}

__global__ void k_dinv(const float* __restrict__ deg, float* dinv, int N){
  int i = blockIdx.x * 256 + threadIdx.x;
  if (i < N){ float d = deg[i]; dinv[i] = d > 0.f ? 1.0f / sqrtf(d) : 0.f; }
}

// single-block exclusive scan of cnt -> row_ptr (and fill copy)
__global__ void k_scan(const int* __restrict__ cnt, int* row_ptr, int* fill, int N){
  __shared__ int sums[1024];
  int t = threadIdx.x;
  int per = (N + 1023) >> 10;
  int base = t * per;
  int s = 0;
  for (int i = 0; i < per; i++){ int idx = base + i; s += (idx < N) ? cnt[idx] : 0; }
  sums[t] = s; __syncthreads();
  for (int off = 1; off < 1024; off <<= 1){
    int v = (t >= off) ? sums[t - off] : 0;
    __syncthreads();
    sums[t] += v;
    __syncthreads();
  }
  int prefix = (t > 0) ? sums[t - 1] : 0;
  for (int i = 0; i < per; i++){
    int idx = base + i;
    if (idx < N){ row_ptr[idx] = prefix; fill[idx] = prefix; prefix += cnt[idx]; }
  }
  if (t == 1023) row_ptr[N] = sums[1023];
}

__global__ void k_fill(const int* __restrict__ row, const int* __restrict__ col,
                       const float* __restrict__ w, const float* __restrict__ dinv,
                       int* fill, int* col_s, float* coef_s, int E){
  int e = blockIdx.x * 256 + threadIdx.x;
  if (e < E){
    int r = row[e], c = col[e];
    int p = atomicAdd(&fill[r], 1);
    col_s[p] = c;
    coef_s[p] = dinv[r] * dinv[c] * w[e];
  }
}

// cur16 = bf16(x); accf = x (fp32)
__global__ void k_init(const float* __restrict__ x, unsigned short* cur16, float* accf, int total){
  int i = blockIdx.x * 256 + threadIdx.x;
  if (i < total){ float v = x[i]; cur16[i] = f2bf(v); accf[i] = v; }
}

// src [N][C] bf16 -> dst [C][N] bf16 (LDS-tiled 64x64)
__global__ void k_transpose(const unsigned short* __restrict__ src, unsigned short* __restrict__ dst, int N){
  __shared__ unsigned short tile[64][66];
  int n0 = blockIdx.x * 64, c0 = blockIdx.y * 64;
  int tx = threadIdx.x & 63;
  int ty = threadIdx.x >> 6;
  for (int r = ty; r < 64; r += 4) tile[r][tx] = src[(size_t)(n0 + r) * C + c0 + tx];
  __syncthreads();
  for (int r = ty; r < 64; r += 4) dst[(size_t)(c0 + r) * N + n0 + tx] = tile[tx][r];
}

// ---------------- projection: q/k = normalize(x @ W^T + b)  [MFMA] ----------------
// wave handles 16 nodes x 128 out channels. transposed=1 writes out[ch][node] (for ksT).
__global__ __launch_bounds__(256) void k_proj(const unsigned short* __restrict__ x,
      const unsigned short* __restrict__ W, const float* __restrict__ Wb,
      unsigned short* __restrict__ out, int N, int transposed){
  int wv = threadIdx.x >> 6, l = threadIdx.x & 63;
  int m0 = (blockIdx.x * 4 + wv) * 16;
  if (m0 >= N) return;
  int quad = l >> 4, lcol = l & 15;
  ffrag acc[8] = {};
  const unsigned short* Abase = x + (size_t)(m0 + lcol) * C + quad * 8;
#pragma unroll
  for (int s = 0; s < 4; s++){
    bfrag a = *(const bfrag*)(Abase + s * 32);
#pragma unroll
    for (int nt = 0; nt < 8; nt++){
      bfrag bb = *(const bfrag*)(W + (size_t)(nt * 16 + lcol) * C + s * 32 + quad * 8);
      acc[nt] = __builtin_amdgcn_mfma_f32_16x16x32_bf16(a, bb, acc[nt], 0, 0, 0);
    }
  }
  float q[8][4];
  float ss[4] = {0.f, 0.f, 0.f, 0.f};
#pragma unroll
  for (int nt = 0; nt < 8; nt++){
    float bias = Wb[nt * 16 + lcol];
#pragma unroll
    for (int r = 0; r < 4; r++){ float v = acc[nt][r] + bias; q[nt][r] = v; ss[r] += v * v; }
  }
#pragma unroll
  for (int off = 1; off < 16; off <<= 1){
#pragma unroll
    for (int r = 0; r < 4; r++) ss[r] += __shfl_xor(ss[r], off, 64);
  }
  float inv[4];
#pragma unroll
  for (int r = 0; r < 4; r++) inv[r] = 1.0f / sqrtf(fmaxf(ss[r], 1e-30f));
  if (!transposed){
#pragma unroll
    for (int nt = 0; nt < 8; nt++)
#pragma unroll
      for (int r = 0; r < 4; r++)
        out[(size_t)(m0 + quad * 4 + r) * C + nt * 16 + lcol] = f2bf(q[nt][r] * inv[r]);
  } else {
#pragma unroll
    for (int nt = 0; nt < 8; nt++){
      ushort4 pk;
      pk.x = f2bf(q[nt][0] * inv[0]); pk.y = f2bf(q[nt][1] * inv[1]);
      pk.z = f2bf(q[nt][2] * inv[2]); pk.w = f2bf(q[nt][3] * inv[3]);
      *(ushort4*)(out + (size_t)(nt * 16 + lcol) * N + m0 + quad * 4) = pk;
    }
  }
}

__global__ void k_ksum(const unsigned short* __restrict__ ksT, float* ksum, int N, int PG){
  int b = blockIdx.x, i = threadIdx.x;
  const unsigned short* p = ksT + (size_t)i * N + (size_t)b * PG;
  float s = 0.f;
  for (int n = 0; n < PG; n++) s += bf2f(p[n]);
  ksum[b * C + i] = s;
}

__global__ void k_denom(const unsigned short* __restrict__ qs, const float* __restrict__ ksum,
                        const int* __restrict__ n_nodes, float* denom, int N, int PG){
  int wv = threadIdx.x >> 6, l = threadIdx.x & 63;
  int m = blockIdx.x * 4 + wv;
  if (m >= N) return;
  int b = m / PG;
  float s = bf2f(qs[(size_t)m * C + l]) * ksum[b * C + l]
          + bf2f(qs[(size_t)m * C + 64 + l]) * ksum[b * C + 64 + l];
#pragma unroll
  for (int off = 32; off; off >>= 1) s += __shfl_xor(s, off, 64);
  if (l == 0) denom[m] = s + (float)n_nodes[b];
}

__global__ void k_vsum(const unsigned short* __restrict__ cur16, float* vsum, int PG){
  int b = blockIdx.x, ch = blockIdx.y, c = threadIdx.x;
  int chunk = PG / 8;
  const unsigned short* p = cur16 + ((size_t)b * PG + ch * chunk) * C + c;
  float s = 0.f;
  for (int n = 0; n < chunk; n++) s += bf2f(p[(size_t)n * C]);
  atomicAdd(&vsum[b * C + c], s);
}

// ---------------- M[b] = Ks_b^T Cur_b -> MT[d][i] (bf16)  [MFMA] ----------------
__global__ __launch_bounds__(256) void k_M(const unsigned short* __restrict__ ksT,
      const unsigned short* __restrict__ curT, unsigned short* __restrict__ MT, int N, int PG){
  int b = blockIdx.y;
  int wv = threadIdx.x >> 6, l = threadIdx.x & 63;
  int gw = blockIdx.x * 4 + wv;
  int itile = gw & 7, jh = gw >> 3;
  int quad = l >> 4, lcol = l & 15;
  ffrag acc[4] = {};
  const unsigned short* Arow = ksT + (size_t)(itile * 16 + lcol) * N + (size_t)b * PG + quad * 8;
  const unsigned short* B0 = curT + (size_t)b * PG + quad * 8;
  int steps = PG / 32;
  for (int s = 0; s < steps; s++){
    bfrag a = *(const bfrag*)(Arow + s * 32);
#pragma unroll
    for (int jt = 0; jt < 4; jt++){
      bfrag bb = *(const bfrag*)(B0 + (size_t)((jh * 4 + jt) * 16 + lcol) * N + s * 32);
      acc[jt] = __builtin_amdgcn_mfma_f32_16x16x32_bf16(a, bb, acc[jt], 0, 0, 0);
    }
  }
  unsigned short* MTb = MT + (size_t)b * C * C;
  int i0 = itile * 16 + quad * 4;
#pragma unroll
  for (int jt = 0; jt < 4; jt++){
    int j = (jh * 4 + jt) * 16 + lcol;
    ushort4 pk;
    pk.x = f2bf(acc[jt][0]); pk.y = f2bf(acc[jt][1]);
    pk.z = f2bf(acc[jt][2]); pk.w = f2bf(acc[jt][3]);
    *(ushort4*)(MTb + (size_t)j * C + i0) = pk;
  }
}

// ---------------- GCN gather (CSR): gcn[n] = sum_e coef*cur[col] ----------------
__global__ void k_gcn(const int* __restrict__ row_ptr, const int* __restrict__ col_s,
                      const float* __restrict__ coef_s, const unsigned short* __restrict__ cur16,
                      unsigned short* __restrict__ gcn16, int N){
  int n = blockIdx.x;
  int c = threadIdx.x;
  int s = row_ptr[n], e = row_ptr[n + 1];
  float acc = 0.f;
  for (int p = s; p < e; p++){
    acc += coef_s[p] * bf2f(cur16[(size_t)col_s[p] * C + c]);
  }
  gcn16[(size_t)n * C + c] = f2bf(acc);
}

// ---------------- phase2: attn=(qs.M+vsum)/denom; combine+accumulate  [MFMA] ----------------
__global__ __launch_bounds__(256) void k_phase2(const unsigned short* __restrict__ qs,
      const unsigned short* __restrict__ MT, const float* __restrict__ vsum,
      const float* __restrict__ denom, const unsigned short* __restrict__ gcn16,
      unsigned short* __restrict__ cur16, unsigned short* __restrict__ curT,
      float* __restrict__ accf, unsigned short* __restrict__ acc16,
      int N, int PG, int last){
  int wv = threadIdx.x >> 6, l = threadIdx.x & 63;
  int m0 = (blockIdx.x * 4 + wv) * 16;
  if (m0 >= N) return;
  int b = m0 / PG;
  int quad = l >> 4, lcol = l & 15;
  ffrag acc[8] = {};
  const unsigned short* Abase = qs + (size_t)(m0 + lcol) * C + quad * 8;
  const unsigned short* MTb = MT + (size_t)b * C * C;
#pragma unroll
  for (int s = 0; s < 4; s++){
    bfrag a = *(const bfrag*)(Abase + s * 32);
#pragma unroll
    for (int dt = 0; dt < 8; dt++){
      bfrag bb = *(const bfrag*)(MTb + (size_t)(dt * 16 + lcol) * C + s * 32 + quad * 8);
      acc[dt] = __builtin_amdgcn_mfma_f32_16x16x32_bf16(a, bb, acc[dt], 0, 0, 0);
    }
  }
  float dn[4];
#pragma unroll
  for (int r = 0; r < 4; r++) dn[r] = denom[m0 + quad * 4 + r];
#pragma unroll
  for (int dt = 0; dt < 8; dt++){
    int d = dt * 16 + lcol;
    float vs = vsum[b * C + d];
    ushort4 pk;
#pragma unroll
    for (int r = 0; r < 4; r++){
      int m = m0 + quad * 4 + r;
      float attn = (acc[dt][r] + vs) / dn[r];
      float g = bf2f(gcn16[(size_t)m * C + d]);
      float nc = 0.5f * (g + attn);           // BETA = 0.5
      float na = accf[(size_t)m * C + d] + nc;
      accf[(size_t)m * C + d] = na;
      unsigned short nb = f2bf(nc);
      cur16[(size_t)m * C + d] = nb;
      if (last) acc16[(size_t)m * C + d] = f2bf(na);
      ((unsigned short*)&pk)[r] = nb;
    }
    *(ushort4*)(curT + (size_t)d * N + m0 + quad * 4) = pk;
  }
}

// ---------------- out = acc @ Wo^T + Wo_b  (FP32 OUTPUT)  [MFMA] ----------------
__global__ __launch_bounds__(256) void k_final(const unsigned short* __restrict__ acc16,
      const unsigned short* __restrict__ Wo, const float* __restrict__ Wob,
      float* __restrict__ out, int N){
  int wv = threadIdx.x >> 6, l = threadIdx.x & 63;
  int m0 = (blockIdx.x * 4 + wv) * 16;
  if (m0 >= N) return;
  int quad = l >> 4, lcol = l & 15;
  ffrag acc[8] = {};
  const unsigned short* Abase = acc16 + (size_t)(m0 + lcol) * C + quad * 8;
#pragma unroll
  for (int s = 0; s < 4; s++){
    bfrag a = *(const bfrag*)(Abase + s * 32);
#pragma unroll
    for (int ot = 0; ot < 8; ot++){
      bfrag bb = *(const bfrag*)(Wo + (size_t)(ot * 16 + lcol) * C + s * 32 + quad * 8);
      acc[ot] = __builtin_amdgcn_mfma_f32_16x16x32_bf16(a, bb, acc[ot], 0, 0, 0);
    }
  }
#pragma unroll
  for (int ot = 0; ot < 8; ot++){
    float bias = Wob[ot * 16 + lcol];
#pragma unroll
    for (int r = 0; r < 4; r++){
      out[(size_t)(m0 + quad * 4 + r) * C + ot * 16 + lcol] = acc[ot][r] + bias;   // fp32 store
    }
  }
}

// ================= host =================

extern "C" void kernel_launch(void* const* d_in, const int* in_sizes, int n_in,
                              void* d_out, int out_size, void* d_ws, size_t ws_size,
                              hipStream_t stream){
  const float* x    = (const float*)d_in[0];
  const int*   eidx = (const int*)d_in[1];
  const float* ew   = (const float*)d_in[2];
  const int*   n_nodes = (const int*)d_in[3];
  const float* Wq_w = (const float*)d_in[4];
  const float* Wq_b = (const float*)d_in[5];
  const float* Wk_w = (const float*)d_in[6];
  const float* Wk_b = (const float*)d_in[7];
  const float* Wo_w = (const float*)d_in[8];
  const float* Wo_b = (const float*)d_in[9];
  float* out = (float*)d_out;                  // fp32 output (R12-verified)

  int N = in_sizes[0] / C;
  int E = in_sizes[2];
  int B = in_sizes[3];
  int PG = N / B;
  const int* row = eidx;
  const int* col = eidx + E;

  char* p = (char*)d_ws;
  auto alloc = [&](size_t bytes) -> void* {
    void* r = (void*)p; p += (bytes + 255) & ~(size_t)255; return r;
  };
  unsigned short* cur16 = (unsigned short*)alloc((size_t)N * C * 2);
  unsigned short* curT  = (unsigned short*)alloc((size_t)N * C * 2);
  unsigned short* qs16  = (unsigned short*)alloc((size_t)N * C * 2);
  unsigned short* ksT   = (unsigned short*)alloc((size_t)N * C * 2);
  unsigned short* gcn16 = (unsigned short*)alloc((size_t)N * C * 2);
  unsigned short* acc16 = (unsigned short*)alloc((size_t)N * C * 2);
  float*          accf  = (float*)alloc((size_t)N * C * 4);
  unsigned short* MT    = (unsigned short*)alloc((size_t)B * C * C * 2);
  unsigned short* Wq16  = (unsigned short*)alloc((size_t)C * C * 2);
  unsigned short* Wk16  = (unsigned short*)alloc((size_t)C * C * 2);
  unsigned short* Wo16  = (unsigned short*)alloc((size_t)C * C * 2);
  float*          deg   = (float*)alloc((size_t)N * 4);
  float*          dinv  = (float*)alloc((size_t)N * 4);
  int*            cnt   = (int*)alloc((size_t)N * 4);
  int*            row_ptr = (int*)alloc((size_t)(N + 1) * 4);
  int*            fill  = (int*)alloc((size_t)N * 4);
  int*            col_s = (int*)alloc((size_t)E * 4);
  float*          coef_s = (float*)alloc((size_t)E * 4);
  float*          ksum  = (float*)alloc((size_t)B * C * 4);
  float*          vsum  = (float*)alloc((size_t)B * C * 4);
  float*          denom = (float*)alloc((size_t)N * 4);

  dim3 b256(256);
  int wblocks = (N / 16 + 3) / 4;   // one wave per 16 nodes, 4 waves/block
  int WW = C * C;

  // loop-invariant prep
  k_zero<<<dim3((N + 255) / 256), b256, 0, stream>>>(deg, cnt, N);
  k_deg<<<dim3((E + 255) / 256), b256, 0, stream>>>(row, ew, deg, cnt, E);
  k_dinv<<<dim3((N + 255) / 256), b256, 0, stream>>>(deg, dinv, N);
  k_scan<<<1, 1024, 0, stream>>>(cnt, row_ptr, fill, N);
  k_fill<<<dim3((E + 255) / 256), b256, 0, stream>>>(row, col, ew, dinv, fill, col_s, coef_s, E);
  k_init<<<dim3((N * C + 255) / 256), b256, 0, stream>>>(x, cur16, accf, N * C);
  k_cast<<<dim3((WW + 255) / 256), b256, 0, stream>>>(Wq_w, Wq16, WW);
  k_cast<<<dim3((WW + 255) / 256), b256, 0, stream>>>(Wk_w, Wk16, WW);
  k_cast<<<dim3((WW + 255) / 256), b256, 0, stream>>>(Wo_w, Wo16, WW);
  k_transpose<<<dim3(N / 64, C / 64), b256, 0, stream>>>(cur16, curT, N);
  k_proj<<<dim3(wblocks), b256, 0, stream>>>(cur16, Wq16, Wq_b, qs16, N, 0);
  k_proj<<<dim3(wblocks), b256, 0, stream>>>(cur16, Wk16, Wk_b, ksT, N, 1);
  k_ksum<<<dim3(B), dim3(C), 0, stream>>>(ksT, ksum, N, PG);
  k_denom<<<dim3((N + 3) / 4), b256, 0, stream>>>(qs16, ksum, n_nodes, denom, N, PG);

  // 4 propagation iterations
  for (int it = 0; it < 4; it++){
    k_zero<<<dim3((B * C + 255) / 256), b256, 0, stream>>>(vsum, (int*)nullptr, B * C);
    k_vsum<<<dim3(B, 8), dim3(C), 0, stream>>>(cur16, vsum, PG);
    k_M<<<dim3(4, B), b256, 0, stream>>>(ksT, curT, MT, N, PG);
    k_gcn<<<dim3(N), dim3(C), 0, stream>>>(row_ptr, col_s, coef_s, cur16, gcn16, N);
    k_phase2<<<dim3(wblocks), b256, 0, stream>>>(qs16, MT, vsum, denom, gcn16,
                                                 cur16, curT, accf, acc16, N, PG, it == 3);
  }

  k_final<<<dim3(wblocks), b256, 0, stream>>>(acc16, Wo16, Wo_b, out, N);
}

// Round 14
// 690.604 us; speedup vs baseline: 5.5339x; 1.1822x over previous
//
#include <hip/hip_runtime.h>
#include <stdint.h>

#define C 128

typedef __attribute__((ext_vector_type(8))) short bfrag;   // 8 x bf16 (4 VGPRs)
typedef __attribute__((ext_vector_type(4))) float ffrag;   // 4 x f32 accum

__device__ __forceinline__ unsigned short f2bf(float f){
  union { float f; unsigned int i; } v; v.f = f;
  unsigned int x = v.i;
  unsigned int r = x + 0x7fffu + ((x >> 16) & 1u);   // round-to-nearest-even
  return (unsigned short)(r >> 16);
}
__device__ __forceinline__ float bf2f(unsigned short u){
  union { unsigned int i; float f; } v; v.i = ((unsigned int)u) << 16; return v.f;
}

// ---------------- misc small kernels ----------------

__global__ void k_zero(float* a, int* b, int n){
  int i = blockIdx.x * 256 + threadIdx.x;
  if (i < n){ if (a) a[i] = 0.f; if (b) b[i] = 0; }
}

__global__ void k_cast(const float* __restrict__ src, unsigned short* __restrict__ dst, int n){
  int i = blockIdx.x * 256 + threadIdx.x;
  if (i < n) dst[i] = f2bf(src[i]);
}

__global__ void k_deg(const int* __restrict__ row, const float* __restrict__ w,
                      float* deg, int* cnt, int E){
  int e = blockIdx.x * 256 + threadIdx.x;
  if (e < E){
    int r = row[e];
    atomicAdd(&deg[r], w[e]);
    atomicAdd(&cnt[r], 1);
  }
}

__global__ void k_dinv(const float* __restrict__ deg, float* dinv, int N){
  int i = blockIdx.x * 256 + threadIdx.x;
  if (i < N){ float d = deg[i]; dinv[i] = d > 0.f ? 1.0f / sqrtf(d) : 0.f; }
}

// ---- 3-stage coalesced scan of cnt -> row_ptr/fill (256 elems per block) ----
__global__ void k_scan1(const int* __restrict__ cnt, int* bsum, int N){
  __shared__ int s[256];
  int b = blockIdx.x, t = threadIdx.x;
  int i = b * 256 + t;
  s[t] = (i < N) ? cnt[i] : 0;
  __syncthreads();
  for (int o = 128; o; o >>= 1){ if (t < o) s[t] += s[t + o]; __syncthreads(); }
  if (t == 0) bsum[b] = s[0];
}
__global__ void k_scan2(const int* __restrict__ bsum, int* bbase, int nb){
  __shared__ int s[256];
  int t = threadIdx.x;
  s[t] = (t < nb) ? bsum[t] : 0;
  __syncthreads();
  for (int o = 1; o < 256; o <<= 1){
    int v = (t >= o) ? s[t - o] : 0;
    __syncthreads(); s[t] += v; __syncthreads();
  }
  if (t < nb) bbase[t] = (t > 0) ? s[t - 1] : 0;   // exclusive
}
__global__ void k_scan3(const int* __restrict__ cnt, const int* __restrict__ bbase,
                        int* row_ptr, int* fill, int N){
  __shared__ int s[256];
  int b = blockIdx.x, t = threadIdx.x;
  int i = b * 256 + t;
  int v = (i < N) ? cnt[i] : 0;
  s[t] = v;
  __syncthreads();
  for (int o = 1; o < 256; o <<= 1){
    int u = (t >= o) ? s[t - o] : 0;
    __syncthreads(); s[t] += u; __syncthreads();
  }
  int excl = bbase[b] + s[t] - v;    // exclusive prefix
  if (i < N){ row_ptr[i] = excl; fill[i] = excl; }
  if (i == N - 1) row_ptr[N] = excl + v;
}

__global__ void k_fill(const int* __restrict__ row, const int* __restrict__ col,
                       const float* __restrict__ w, const float* __restrict__ dinv,
                       int* fill, int* col_s, float* coef_s, int E){
  int e = blockIdx.x * 256 + threadIdx.x;
  if (e < E){
    int r = row[e], c = col[e];
    int p = atomicAdd(&fill[r], 1);
    col_s[p] = c;
    coef_s[p] = dinv[r] * dinv[c] * w[e];
  }
}

// cur16 = bf16(x); accf = x (fp32)
__global__ void k_init(const float* __restrict__ x, unsigned short* cur16, float* accf, int total){
  int i = blockIdx.x * 256 + threadIdx.x;
  if (i < total){ float v = x[i]; cur16[i] = f2bf(v); accf[i] = v; }
}

// src [N][C] bf16 -> dst [C][N] bf16 (LDS-tiled 64x64)
__global__ void k_transpose(const unsigned short* __restrict__ src, unsigned short* __restrict__ dst, int N){
  __shared__ unsigned short tile[64][66];
  int n0 = blockIdx.x * 64, c0 = blockIdx.y * 64;
  int tx = threadIdx.x & 63;
  int ty = threadIdx.x >> 6;
  for (int r = ty; r < 64; r += 4) tile[r][tx] = src[(size_t)(n0 + r) * C + c0 + tx];
  __syncthreads();
  for (int r = ty; r < 64; r += 4) dst[(size_t)(c0 + r) * N + n0 + tx] = tile[tx][r];
}

// ---------------- projection [MFMA]; transposed=1 also accumulates ksum ----------------
__global__ __launch_bounds__(256) void k_proj(const unsigned short* __restrict__ x,
      const unsigned short* __restrict__ W, const float* __restrict__ Wb,
      unsigned short* __restrict__ out, float* __restrict__ ksum,
      int N, int PG, int transposed){
  int wv = threadIdx.x >> 6, l = threadIdx.x & 63;
  int m0 = (blockIdx.x * 4 + wv) * 16;
  if (m0 >= N) return;
  int quad = l >> 4, lcol = l & 15;
  ffrag acc[8] = {};
  const unsigned short* Abase = x + (size_t)(m0 + lcol) * C + quad * 8;
#pragma unroll
  for (int s = 0; s < 4; s++){
    bfrag a = *(const bfrag*)(Abase + s * 32);
#pragma unroll
    for (int nt = 0; nt < 8; nt++){
      bfrag bb = *(const bfrag*)(W + (size_t)(nt * 16 + lcol) * C + s * 32 + quad * 8);
      acc[nt] = __builtin_amdgcn_mfma_f32_16x16x32_bf16(a, bb, acc[nt], 0, 0, 0);
    }
  }
  float q[8][4];
  float ss[4] = {0.f, 0.f, 0.f, 0.f};
#pragma unroll
  for (int nt = 0; nt < 8; nt++){
    float bias = Wb[nt * 16 + lcol];
#pragma unroll
    for (int r = 0; r < 4; r++){ float v = acc[nt][r] + bias; q[nt][r] = v; ss[r] += v * v; }
  }
#pragma unroll
  for (int off = 1; off < 16; off <<= 1){
#pragma unroll
    for (int r = 0; r < 4; r++) ss[r] += __shfl_xor(ss[r], off, 64);
  }
  float inv[4];
#pragma unroll
  for (int r = 0; r < 4; r++) inv[r] = 1.0f / sqrtf(fmaxf(ss[r], 1e-30f));
  if (!transposed){
#pragma unroll
    for (int nt = 0; nt < 8; nt++)
#pragma unroll
      for (int r = 0; r < 4; r++)
        out[(size_t)(m0 + quad * 4 + r) * C + nt * 16 + lcol] = f2bf(q[nt][r] * inv[r]);
  } else {
    int b = m0 / PG;
#pragma unroll
    for (int nt = 0; nt < 8; nt++){
      ushort4 pk;
      float v0 = q[nt][0] * inv[0], v1 = q[nt][1] * inv[1];
      float v2 = q[nt][2] * inv[2], v3 = q[nt][3] * inv[3];
      pk.x = f2bf(v0); pk.y = f2bf(v1); pk.z = f2bf(v2); pk.w = f2bf(v3);
      *(ushort4*)(out + (size_t)(nt * 16 + lcol) * N + m0 + quad * 4) = pk;
      // fold ksum: sum the 16 nodes of this wave for channel nt*16+lcol
      float s = v0 + v1 + v2 + v3;
      s += __shfl_xor(s, 16, 64);
      s += __shfl_xor(s, 32, 64);
      if (quad == 0) atomicAdd(&ksum[b * C + nt * 16 + lcol], s);
    }
  }
}

__global__ void k_denom(const unsigned short* __restrict__ qs, const float* __restrict__ ksum,
                        const int* __restrict__ n_nodes, float* denom, int N, int PG){
  int wv = threadIdx.x >> 6, l = threadIdx.x & 63;
  int m = blockIdx.x * 4 + wv;
  if (m >= N) return;
  int b = m / PG;
  float s = bf2f(qs[(size_t)m * C + l]) * ksum[b * C + l]
          + bf2f(qs[(size_t)m * C + 64 + l]) * ksum[b * C + 64 + l];
#pragma unroll
  for (int off = 32; off; off >>= 1) s += __shfl_xor(s, off, 64);
  if (l == 0) denom[m] = s + (float)n_nodes[b];
}

__global__ void k_vsum(const unsigned short* __restrict__ cur16, float* vsum, int PG){
  int b = blockIdx.x, ch = blockIdx.y, c = threadIdx.x;
  int chunk = PG / 8;
  const unsigned short* p = cur16 + ((size_t)b * PG + ch * chunk) * C + c;
  float s = 0.f;
  for (int n = 0; n < chunk; n++) s += bf2f(p[(size_t)n * C]);
  atomicAdd(&vsum[b * C + c], s);
}

// ---------------- M[b] = Ks_b^T Cur_b -> MT[d][i] (bf16)  [MFMA] ----------------
__global__ __launch_bounds__(256) void k_M(const unsigned short* __restrict__ ksT,
      const unsigned short* __restrict__ curT, unsigned short* __restrict__ MT, int N, int PG){
  int b = blockIdx.y;
  int wv = threadIdx.x >> 6, l = threadIdx.x & 63;
  int gw = blockIdx.x * 4 + wv;
  int itile = gw & 7, jh = gw >> 3;
  int quad = l >> 4, lcol = l & 15;
  ffrag acc[4] = {};
  const unsigned short* Arow = ksT + (size_t)(itile * 16 + lcol) * N + (size_t)b * PG + quad * 8;
  const unsigned short* B0 = curT + (size_t)b * PG + quad * 8;
  int steps = PG / 32;
  for (int s = 0; s < steps; s++){
    bfrag a = *(const bfrag*)(Arow + s * 32);
#pragma unroll
    for (int jt = 0; jt < 4; jt++){
      bfrag bb = *(const bfrag*)(B0 + (size_t)((jh * 4 + jt) * 16 + lcol) * N + s * 32);
      acc[jt] = __builtin_amdgcn_mfma_f32_16x16x32_bf16(a, bb, acc[jt], 0, 0, 0);
    }
  }
  unsigned short* MTb = MT + (size_t)b * C * C;
  int i0 = itile * 16 + quad * 4;
#pragma unroll
  for (int jt = 0; jt < 4; jt++){
    int j = (jh * 4 + jt) * 16 + lcol;
    ushort4 pk;
    pk.x = f2bf(acc[jt][0]); pk.y = f2bf(acc[jt][1]);
    pk.z = f2bf(acc[jt][2]); pk.w = f2bf(acc[jt][3]);
    *(ushort4*)(MTb + (size_t)j * C + i0) = pk;
  }
}

// ---------------- GCN gather (CSR), uint-vectorized: 4 nodes/block ----------------
__global__ __launch_bounds__(256) void k_gcn(const int* __restrict__ row_ptr,
                      const int* __restrict__ col_s, const float* __restrict__ coef_s,
                      const unsigned int* __restrict__ cur32,
                      unsigned int* __restrict__ gcn32, int N){
  int nid = blockIdx.x * 4 + (threadIdx.x >> 6);
  int c = threadIdx.x & 63;                 // channel-pair index
  if (nid >= N) return;
  int s = row_ptr[nid], e = row_ptr[nid + 1];
  float a0 = 0.f, a1 = 0.f;
  for (int p = s; p < e; p++){
    float cf = coef_s[p];
    unsigned int u = cur32[(size_t)col_s[p] * 64 + c];
    a0 += cf * bf2f((unsigned short)(u & 0xffffu));
    a1 += cf * bf2f((unsigned short)(u >> 16));
  }
  gcn32[(size_t)nid * 64 + c] = ((unsigned int)f2bf(a1) << 16) | (unsigned int)f2bf(a0);
}

// ---------------- phase2: attn=(qs.M+vsum)/denom; combine+accumulate  [MFMA] ----------------
__global__ __launch_bounds__(256) void k_phase2(const unsigned short* __restrict__ qs,
      const unsigned short* __restrict__ MT, const float* __restrict__ vsum,
      const float* __restrict__ denom, const unsigned short* __restrict__ gcn16,
      unsigned short* __restrict__ cur16, unsigned short* __restrict__ curT,
      float* __restrict__ accf, unsigned short* __restrict__ acc16,
      int N, int PG, int last){
  int wv = threadIdx.x >> 6, l = threadIdx.x & 63;
  int m0 = (blockIdx.x * 4 + wv) * 16;
  if (m0 >= N) return;
  int b = m0 / PG;
  int quad = l >> 4, lcol = l & 15;
  ffrag acc[8] = {};
  const unsigned short* Abase = qs + (size_t)(m0 + lcol) * C + quad * 8;
  const unsigned short* MTb = MT + (size_t)b * C * C;
#pragma unroll
  for (int s = 0; s < 4; s++){
    bfrag a = *(const bfrag*)(Abase + s * 32);
#pragma unroll
    for (int dt = 0; dt < 8; dt++){
      bfrag bb = *(const bfrag*)(MTb + (size_t)(dt * 16 + lcol) * C + s * 32 + quad * 8);
      acc[dt] = __builtin_amdgcn_mfma_f32_16x16x32_bf16(a, bb, acc[dt], 0, 0, 0);
    }
  }
  float dn[4];
#pragma unroll
  for (int r = 0; r < 4; r++) dn[r] = denom[m0 + quad * 4 + r];
#pragma unroll
  for (int dt = 0; dt < 8; dt++){
    int d = dt * 16 + lcol;
    float vs = vsum[b * C + d];
    ushort4 pk;
#pragma unroll
    for (int r = 0; r < 4; r++){
      int m = m0 + quad * 4 + r;
      float attn = (acc[dt][r] + vs) / dn[r];
      float g = bf2f(gcn16[(size_t)m * C + d]);
      float nc = 0.5f * (g + attn);           // BETA = 0.5
      float na = accf[(size_t)m * C + d] + nc;
      accf[(size_t)m * C + d] = na;
      unsigned short nb = f2bf(nc);
      cur16[(size_t)m * C + d] = nb;
      if (last) acc16[(size_t)m * C + d] = f2bf(na);
      ((unsigned short*)&pk)[r] = nb;
    }
    *(ushort4*)(curT + (size_t)d * N + m0 + quad * 4) = pk;
  }
}

// ---------------- out = acc @ Wo^T + Wo_b  (FP32 OUTPUT)  [MFMA] ----------------
__global__ __launch_bounds__(256) void k_final(const unsigned short* __restrict__ acc16,
      const unsigned short* __restrict__ Wo, const float* __restrict__ Wob,
      float* __restrict__ out, int N){
  int wv = threadIdx.x >> 6, l = threadIdx.x & 63;
  int m0 = (blockIdx.x * 4 + wv) * 16;
  if (m0 >= N) return;
  int quad = l >> 4, lcol = l & 15;
  ffrag acc[8] = {};
  const unsigned short* Abase = acc16 + (size_t)(m0 + lcol) * C + quad * 8;
#pragma unroll
  for (int s = 0; s < 4; s++){
    bfrag a = *(const bfrag*)(Abase + s * 32);
#pragma unroll
    for (int ot = 0; ot < 8; ot++){
      bfrag bb = *(const bfrag*)(Wo + (size_t)(ot * 16 + lcol) * C + s * 32 + quad * 8);
      acc[ot] = __builtin_amdgcn_mfma_f32_16x16x32_bf16(a, bb, acc[ot], 0, 0, 0);
    }
  }
#pragma unroll
  for (int ot = 0; ot < 8; ot++){
    float bias = Wob[ot * 16 + lcol];
#pragma unroll
    for (int r = 0; r < 4; r++){
      out[(size_t)(m0 + quad * 4 + r) * C + ot * 16 + lcol] = acc[ot][r] + bias;   // fp32 store
    }
  }
}

// ================= host =================

extern "C" void kernel_launch(void* const* d_in, const int* in_sizes, int n_in,
                              void* d_out, int out_size, void* d_ws, size_t ws_size,
                              hipStream_t stream){
  const float* x    = (const float*)d_in[0];
  const int*   eidx = (const int*)d_in[1];
  const float* ew   = (const float*)d_in[2];
  const int*   n_nodes = (const int*)d_in[3];
  const float* Wq_w = (const float*)d_in[4];
  const float* Wq_b = (const float*)d_in[5];
  const float* Wk_w = (const float*)d_in[6];
  const float* Wk_b = (const float*)d_in[7];
  const float* Wo_w = (const float*)d_in[8];
  const float* Wo_b = (const float*)d_in[9];
  float* out = (float*)d_out;                  // fp32 output

  int N = in_sizes[0] / C;
  int E = in_sizes[2];
  int B = in_sizes[3];
  int PG = N / B;
  const int* row = eidx;
  const int* col = eidx + E;

  char* p = (char*)d_ws;
  auto alloc = [&](size_t bytes) -> void* {
    void* r = (void*)p; p += (bytes + 255) & ~(size_t)255; return r;
  };
  unsigned short* cur16 = (unsigned short*)alloc((size_t)N * C * 2);
  unsigned short* curT  = (unsigned short*)alloc((size_t)N * C * 2);
  unsigned short* qs16  = (unsigned short*)alloc((size_t)N * C * 2);
  unsigned short* ksT   = (unsigned short*)alloc((size_t)N * C * 2);
  unsigned short* gcn16 = (unsigned short*)alloc((size_t)N * C * 2);
  unsigned short* acc16 = (unsigned short*)alloc((size_t)N * C * 2);
  float*          accf  = (float*)alloc((size_t)N * C * 4);
  unsigned short* MT    = (unsigned short*)alloc((size_t)B * C * C * 2);
  unsigned short* Wq16  = (unsigned short*)alloc((size_t)C * C * 2);
  unsigned short* Wk16  = (unsigned short*)alloc((size_t)C * C * 2);
  unsigned short* Wo16  = (unsigned short*)alloc((size_t)C * C * 2);
  float*          deg   = (float*)alloc((size_t)N * 4);
  float*          dinv  = (float*)alloc((size_t)N * 4);
  int*            cnt   = (int*)alloc((size_t)N * 4);
  int*            row_ptr = (int*)alloc((size_t)(N + 1) * 4);
  int*            fill  = (int*)alloc((size_t)N * 4);
  int*            bsum  = (int*)alloc(1024);
  int*            bbase = (int*)alloc(1024);
  int*            col_s = (int*)alloc((size_t)E * 4);
  float*          coef_s = (float*)alloc((size_t)E * 4);
  float*          ksum  = (float*)alloc((size_t)B * C * 4);
  float*          vsum  = (float*)alloc((size_t)B * C * 4);
  float*          denom = (float*)alloc((size_t)N * 4);

  dim3 b256(256);
  int wblocks = (N / 16 + 3) / 4;   // one wave per 16 nodes, 4 waves/block
  int WW = C * C;
  int nscan = (N + 255) / 256;      // 128 scan blocks

  // loop-invariant prep
  k_zero<<<dim3((N + 255) / 256), b256, 0, stream>>>(deg, cnt, N);
  k_zero<<<dim3((B * C + 255) / 256), b256, 0, stream>>>(ksum, (int*)nullptr, B * C);
  k_deg<<<dim3((E + 255) / 256), b256, 0, stream>>>(row, ew, deg, cnt, E);
  k_dinv<<<dim3((N + 255) / 256), b256, 0, stream>>>(deg, dinv, N);
  k_scan1<<<dim3(nscan), b256, 0, stream>>>(cnt, bsum, N);
  k_scan2<<<1, b256, 0, stream>>>(bsum, bbase, nscan);
  k_scan3<<<dim3(nscan), b256, 0, stream>>>(cnt, bbase, row_ptr, fill, N);
  k_fill<<<dim3((E + 255) / 256), b256, 0, stream>>>(row, col, ew, dinv, fill, col_s, coef_s, E);
  k_init<<<dim3((N * C + 255) / 256), b256, 0, stream>>>(x, cur16, accf, N * C);
  k_cast<<<dim3((WW + 255) / 256), b256, 0, stream>>>(Wq_w, Wq16, WW);
  k_cast<<<dim3((WW + 255) / 256), b256, 0, stream>>>(Wk_w, Wk16, WW);
  k_cast<<<dim3((WW + 255) / 256), b256, 0, stream>>>(Wo_w, Wo16, WW);
  k_transpose<<<dim3(N / 64, C / 64), b256, 0, stream>>>(cur16, curT, N);
  k_proj<<<dim3(wblocks), b256, 0, stream>>>(cur16, Wq16, Wq_b, qs16, (float*)nullptr, N, PG, 0);
  k_proj<<<dim3(wblocks), b256, 0, stream>>>(cur16, Wk16, Wk_b, ksT, ksum, N, PG, 1);
  k_denom<<<dim3((N + 3) / 4), b256, 0, stream>>>(qs16, ksum, n_nodes, denom, N, PG);

  // 4 propagation iterations
  for (int it = 0; it < 4; it++){
    k_zero<<<dim3((B * C + 255) / 256), b256, 0, stream>>>(vsum, (int*)nullptr, B * C);
    k_vsum<<<dim3(B, 8), dim3(C), 0, stream>>>(cur16, vsum, PG);
    k_M<<<dim3(4, B), b256, 0, stream>>>(ksT, curT, MT, N, PG);
    k_gcn<<<dim3((N + 3) / 4), b256, 0, stream>>>(row_ptr, col_s, coef_s,
                                                  (const unsigned int*)cur16,
                                                  (unsigned int*)gcn16, N);
    k_phase2<<<dim3(wblocks), b256, 0, stream>>>(qs16, MT, vsum, denom, gcn16,
                                                 cur16, curT, accf, acc16, N, PG, it == 3);
  }

  k_final<<<dim3(wblocks), b256, 0, stream>>>(acc16, Wo16, Wo_b, out, N);
}

// Round 15
// 535.788 us; speedup vs baseline: 7.1329x; 1.2890x over previous
//
#include <hip/hip_runtime.h>
#include <stdint.h>

#define C 128

typedef __attribute__((ext_vector_type(8))) short bfrag;   // 8 x bf16 (4 VGPRs)
typedef __attribute__((ext_vector_type(4))) float ffrag;   // 4 x f32 accum

__device__ __forceinline__ unsigned short f2bf(float f){
  union { float f; unsigned int i; } v; v.f = f;
  unsigned int x = v.i;
  unsigned int r = x + 0x7fffu + ((x >> 16) & 1u);   // round-to-nearest-even
  return (unsigned short)(r >> 16);
}
__device__ __forceinline__ float bf2f(unsigned short u){
  union { unsigned int i; float f; } v; v.i = ((unsigned int)u) << 16; return v.f;
}

// ---------------- misc small kernels ----------------

__global__ void k_zero(float* a, int* b, int n){
  int i = blockIdx.x * 256 + threadIdx.x;
  if (i < n){ if (a) a[i] = 0.f; if (b) b[i] = 0; }
}

__global__ void k_cast(const float* __restrict__ src, unsigned short* __restrict__ dst, int n){
  int i = blockIdx.x * 256 + threadIdx.x;
  if (i < n) dst[i] = f2bf(src[i]);
}

__global__ void k_deg(const int* __restrict__ row, const float* __restrict__ w,
                      float* deg, int* cnt, int E){
  int e = blockIdx.x * 256 + threadIdx.x;
  if (e < E){
    int r = row[e];
    atomicAdd(&deg[r], w[e]);
    atomicAdd(&cnt[r], 1);
  }
}

__global__ void k_dinv(const float* __restrict__ deg, float* dinv, int N){
  int i = blockIdx.x * 256 + threadIdx.x;
  if (i < N){ float d = deg[i]; dinv[i] = d > 0.f ? 1.0f / sqrtf(d) : 0.f; }
}

// ---- 3-stage coalesced scan of cnt -> row_ptr/fill ----
__global__ void k_scan1(const int* __restrict__ cnt, int* bsum, int N){
  __shared__ int s[256];
  int b = blockIdx.x, t = threadIdx.x;
  int i = b * 256 + t;
  s[t] = (i < N) ? cnt[i] : 0;
  __syncthreads();
  for (int o = 128; o; o >>= 1){ if (t < o) s[t] += s[t + o]; __syncthreads(); }
  if (t == 0) bsum[b] = s[0];
}
__global__ void k_scan2(const int* __restrict__ bsum, int* bbase, int nb){
  __shared__ int s[256];
  int t = threadIdx.x;
  s[t] = (t < nb) ? bsum[t] : 0;
  __syncthreads();
  for (int o = 1; o < 256; o <<= 1){
    int v = (t >= o) ? s[t - o] : 0;
    __syncthreads(); s[t] += v; __syncthreads();
  }
  if (t < nb) bbase[t] = (t > 0) ? s[t - 1] : 0;   // exclusive
}
__global__ void k_scan3(const int* __restrict__ cnt, const int* __restrict__ bbase,
                        int* row_ptr, int* fill, int N){
  __shared__ int s[256];
  int b = blockIdx.x, t = threadIdx.x;
  int i = b * 256 + t;
  int v = (i < N) ? cnt[i] : 0;
  s[t] = v;
  __syncthreads();
  for (int o = 1; o < 256; o <<= 1){
    int u = (t >= o) ? s[t - o] : 0;
    __syncthreads(); s[t] += u; __syncthreads();
  }
  int excl = bbase[b] + s[t] - v;
  if (i < N){ row_ptr[i] = excl; fill[i] = excl; }
  if (i == N - 1) row_ptr[N] = excl + v;
}

__global__ void k_fill(const int* __restrict__ row, const int* __restrict__ col,
                       const float* __restrict__ w, const float* __restrict__ dinv,
                       int* fill, int* col_s, float* coef_s, int E){
  int e = blockIdx.x * 256 + threadIdx.x;
  if (e < E){
    int r = row[e], c = col[e];
    int p = atomicAdd(&fill[r], 1);
    col_s[p] = c;
    coef_s[p] = dinv[r] * dinv[c] * w[e];
  }
}

// cur16 = bf16(x); accf = x (fp32)
__global__ void k_init(const float* __restrict__ x, unsigned short* cur16, float* accf, int total){
  int i = blockIdx.x * 256 + threadIdx.x;
  if (i < total){ float v = x[i]; cur16[i] = f2bf(v); accf[i] = v; }
}

// src [N][C] bf16 -> dst [C][N] bf16 (LDS-tiled 64x64)
__global__ void k_transpose(const unsigned short* __restrict__ src, unsigned short* __restrict__ dst, int N){
  __shared__ unsigned short tile[64][66];
  int n0 = blockIdx.x * 64, c0 = blockIdx.y * 64;
  int tx = threadIdx.x & 63;
  int ty = threadIdx.x >> 6;
  for (int r = ty; r < 64; r += 4) tile[r][tx] = src[(size_t)(n0 + r) * C + c0 + tx];
  __syncthreads();
  for (int r = ty; r < 64; r += 4) dst[(size_t)(c0 + r) * N + n0 + tx] = tile[tx][r];
}

// ---------------- projection [MFMA]; transposed=1 also accumulates ksum ----------------
__global__ __launch_bounds__(256) void k_proj(const unsigned short* __restrict__ x,
      const unsigned short* __restrict__ W, const float* __restrict__ Wb,
      unsigned short* __restrict__ out, float* __restrict__ ksum,
      int N, int PG, int transposed){
  int wv = threadIdx.x >> 6, l = threadIdx.x & 63;
  int m0 = (blockIdx.x * 4 + wv) * 16;
  if (m0 >= N) return;
  int quad = l >> 4, lcol = l & 15;
  ffrag acc[8] = {};
  const unsigned short* Abase = x + (size_t)(m0 + lcol) * C + quad * 8;
#pragma unroll
  for (int s = 0; s < 4; s++){
    bfrag a = *(const bfrag*)(Abase + s * 32);
#pragma unroll
    for (int nt = 0; nt < 8; nt++){
      bfrag bb = *(const bfrag*)(W + (size_t)(nt * 16 + lcol) * C + s * 32 + quad * 8);
      acc[nt] = __builtin_amdgcn_mfma_f32_16x16x32_bf16(a, bb, acc[nt], 0, 0, 0);
    }
  }
  float q[8][4];
  float ss[4] = {0.f, 0.f, 0.f, 0.f};
#pragma unroll
  for (int nt = 0; nt < 8; nt++){
    float bias = Wb[nt * 16 + lcol];
#pragma unroll
    for (int r = 0; r < 4; r++){ float v = acc[nt][r] + bias; q[nt][r] = v; ss[r] += v * v; }
  }
#pragma unroll
  for (int off = 1; off < 16; off <<= 1){
#pragma unroll
    for (int r = 0; r < 4; r++) ss[r] += __shfl_xor(ss[r], off, 64);
  }
  float inv[4];
#pragma unroll
  for (int r = 0; r < 4; r++) inv[r] = 1.0f / sqrtf(fmaxf(ss[r], 1e-30f));
  if (!transposed){
#pragma unroll
    for (int nt = 0; nt < 8; nt++)
#pragma unroll
      for (int r = 0; r < 4; r++)
        out[(size_t)(m0 + quad * 4 + r) * C + nt * 16 + lcol] = f2bf(q[nt][r] * inv[r]);
  } else {
    int b = m0 / PG;
#pragma unroll
    for (int nt = 0; nt < 8; nt++){
      ushort4 pk;
      float v0 = q[nt][0] * inv[0], v1 = q[nt][1] * inv[1];
      float v2 = q[nt][2] * inv[2], v3 = q[nt][3] * inv[3];
      pk.x = f2bf(v0); pk.y = f2bf(v1); pk.z = f2bf(v2); pk.w = f2bf(v3);
      *(ushort4*)(out + (size_t)(nt * 16 + lcol) * N + m0 + quad * 4) = pk;
      float s = v0 + v1 + v2 + v3;
      s += __shfl_xor(s, 16, 64);
      s += __shfl_xor(s, 32, 64);
      if (quad == 0) atomicAdd(&ksum[b * C + nt * 16 + lcol], s);
    }
  }
}

__global__ void k_denom(const unsigned short* __restrict__ qs, const float* __restrict__ ksum,
                        const int* __restrict__ n_nodes, float* denom, int N, int PG){
  int wv = threadIdx.x >> 6, l = threadIdx.x & 63;
  int m = blockIdx.x * 4 + wv;
  if (m >= N) return;
  int b = m / PG;
  float s = bf2f(qs[(size_t)m * C + l]) * ksum[b * C + l]
          + bf2f(qs[(size_t)m * C + 64 + l]) * ksum[b * C + 64 + l];
#pragma unroll
  for (int off = 32; off; off >>= 1) s += __shfl_xor(s, off, 64);
  if (l == 0) denom[m] = s + (float)n_nodes[b];
}

// vsum of initial cur (only used once in prep)
__global__ void k_vsum(const unsigned short* __restrict__ cur16, float* vsum, int PG){
  int b = blockIdx.x, ch = blockIdx.y, c = threadIdx.x;
  int chunk = PG / 8;
  const unsigned short* p = cur16 + ((size_t)b * PG + ch * chunk) * C + c;
  float s = 0.f;
  for (int n = 0; n < chunk; n++) s += bf2f(p[(size_t)n * C]);
  atomicAdd(&vsum[b * C + c], s);
}

// ---------------- M[b] = Ks_b^T Cur_b -> MT[d][i] (bf16)  [MFMA] ----------------
__global__ __launch_bounds__(256) void k_M(const unsigned short* __restrict__ ksT,
      const unsigned short* __restrict__ curT, unsigned short* __restrict__ MT, int N, int PG){
  int b = blockIdx.y;
  int wv = threadIdx.x >> 6, l = threadIdx.x & 63;
  int gw = blockIdx.x * 4 + wv;
  int itile = gw & 7, jh = gw >> 3;
  int quad = l >> 4, lcol = l & 15;
  ffrag acc[4] = {};
  const unsigned short* Arow = ksT + (size_t)(itile * 16 + lcol) * N + (size_t)b * PG + quad * 8;
  const unsigned short* B0 = curT + (size_t)b * PG + quad * 8;
  int steps = PG / 32;
  for (int s = 0; s < steps; s++){
    bfrag a = *(const bfrag*)(Arow + s * 32);
#pragma unroll
    for (int jt = 0; jt < 4; jt++){
      bfrag bb = *(const bfrag*)(B0 + (size_t)((jh * 4 + jt) * 16 + lcol) * N + s * 32);
      acc[jt] = __builtin_amdgcn_mfma_f32_16x16x32_bf16(a, bb, acc[jt], 0, 0, 0);
    }
  }
  unsigned short* MTb = MT + (size_t)b * C * C;
  int i0 = itile * 16 + quad * 4;
#pragma unroll
  for (int jt = 0; jt < 4; jt++){
    int j = (jh * 4 + jt) * 16 + lcol;
    ushort4 pk;
    pk.x = f2bf(acc[jt][0]); pk.y = f2bf(acc[jt][1]);
    pk.z = f2bf(acc[jt][2]); pk.w = f2bf(acc[jt][3]);
    *(ushort4*)(MTb + (size_t)j * C + i0) = pk;
  }
}

// ---------------- GCN gather (CSR), 4-edge unrolled for MLP ----------------
__global__ __launch_bounds__(256) void k_gcn(const int* __restrict__ row_ptr,
                      const int* __restrict__ col_s, const float* __restrict__ coef_s,
                      const unsigned int* __restrict__ cur32,
                      unsigned int* __restrict__ gcn32, int N){
  int nid = blockIdx.x * 4 + (threadIdx.x >> 6);
  int c = threadIdx.x & 63;                 // channel-pair index
  if (nid >= N) return;
  int s = row_ptr[nid], e = row_ptr[nid + 1];
  float a0 = 0.f, a1 = 0.f;
  int p = s;
  for (; p + 4 <= e; p += 4){
    int c0 = col_s[p], c1 = col_s[p + 1], c2 = col_s[p + 2], c3 = col_s[p + 3];
    float f0 = coef_s[p], f1 = coef_s[p + 1], f2 = coef_s[p + 2], f3 = coef_s[p + 3];
    unsigned int u0 = cur32[(size_t)c0 * 64 + c];
    unsigned int u1 = cur32[(size_t)c1 * 64 + c];
    unsigned int u2 = cur32[(size_t)c2 * 64 + c];
    unsigned int u3 = cur32[(size_t)c3 * 64 + c];
    a0 += f0 * bf2f((unsigned short)(u0 & 0xffffu));
    a1 += f0 * bf2f((unsigned short)(u0 >> 16));
    a0 += f1 * bf2f((unsigned short)(u1 & 0xffffu));
    a1 += f1 * bf2f((unsigned short)(u1 >> 16));
    a0 += f2 * bf2f((unsigned short)(u2 & 0xffffu));
    a1 += f2 * bf2f((unsigned short)(u2 >> 16));
    a0 += f3 * bf2f((unsigned short)(u3 & 0xffffu));
    a1 += f3 * bf2f((unsigned short)(u3 >> 16));
  }
  for (; p < e; p++){
    float cf = coef_s[p];
    unsigned int u = cur32[(size_t)col_s[p] * 64 + c];
    a0 += cf * bf2f((unsigned short)(u & 0xffffu));
    a1 += cf * bf2f((unsigned short)(u >> 16));
  }
  gcn32[(size_t)nid * 64 + c] = ((unsigned int)f2bf(a1) << 16) | (unsigned int)f2bf(a0);
}

// ---------------- phase2 [MFMA]; also folds next-iteration vsum ----------------
__global__ __launch_bounds__(256) void k_phase2(const unsigned short* __restrict__ qs,
      const unsigned short* __restrict__ MT, const float* __restrict__ vsum,
      const float* __restrict__ denom, const unsigned short* __restrict__ gcn16,
      unsigned short* __restrict__ cur16, unsigned short* __restrict__ curT,
      float* __restrict__ accf, unsigned short* __restrict__ acc16,
      float* __restrict__ vsumN,           // next-iter vsum accumulator (nullptr on last)
      int N, int PG, int last){
  int wv = threadIdx.x >> 6, l = threadIdx.x & 63;
  int m0 = (blockIdx.x * 4 + wv) * 16;
  if (m0 >= N) return;
  int b = m0 / PG;
  int quad = l >> 4, lcol = l & 15;
  ffrag acc[8] = {};
  const unsigned short* Abase = qs + (size_t)(m0 + lcol) * C + quad * 8;
  const unsigned short* MTb = MT + (size_t)b * C * C;
#pragma unroll
  for (int s = 0; s < 4; s++){
    bfrag a = *(const bfrag*)(Abase + s * 32);
#pragma unroll
    for (int dt = 0; dt < 8; dt++){
      bfrag bb = *(const bfrag*)(MTb + (size_t)(dt * 16 + lcol) * C + s * 32 + quad * 8);
      acc[dt] = __builtin_amdgcn_mfma_f32_16x16x32_bf16(a, bb, acc[dt], 0, 0, 0);
    }
  }
  float dn[4];
#pragma unroll
  for (int r = 0; r < 4; r++) dn[r] = denom[m0 + quad * 4 + r];
#pragma unroll
  for (int dt = 0; dt < 8; dt++){
    int d = dt * 16 + lcol;
    float vs = vsum[b * C + d];
    ushort4 pk;
    float vnext = 0.f;
#pragma unroll
    for (int r = 0; r < 4; r++){
      int m = m0 + quad * 4 + r;
      float attn = (acc[dt][r] + vs) / dn[r];
      float g = bf2f(gcn16[(size_t)m * C + d]);
      float nc = 0.5f * (g + attn);           // BETA = 0.5
      float na = accf[(size_t)m * C + d] + nc;
      accf[(size_t)m * C + d] = na;
      unsigned short nb = f2bf(nc);
      cur16[(size_t)m * C + d] = nb;
      if (last) acc16[(size_t)m * C + d] = f2bf(na);
      ((unsigned short*)&pk)[r] = nb;
      vnext += bf2f(nb);
    }
    *(ushort4*)(curT + (size_t)d * N + m0 + quad * 4) = pk;
    if (vsumN){
      vnext += __shfl_xor(vnext, 16, 64);
      vnext += __shfl_xor(vnext, 32, 64);
      if (quad == 0) atomicAdd(&vsumN[b * C + d], vnext);
    }
  }
}

// ---------------- out = acc @ Wo^T + Wo_b  (FP32 OUTPUT)  [MFMA] ----------------
__global__ __launch_bounds__(256) void k_final(const unsigned short* __restrict__ acc16,
      const unsigned short* __restrict__ Wo, const float* __restrict__ Wob,
      float* __restrict__ out, int N){
  int wv = threadIdx.x >> 6, l = threadIdx.x & 63;
  int m0 = (blockIdx.x * 4 + wv) * 16;
  if (m0 >= N) return;
  int quad = l >> 4, lcol = l & 15;
  ffrag acc[8] = {};
  const unsigned short* Abase = acc16 + (size_t)(m0 + lcol) * C + quad * 8;
#pragma unroll
  for (int s = 0; s < 4; s++){
    bfrag a = *(const bfrag*)(Abase + s * 32);
#pragma unroll
    for (int ot = 0; ot < 8; ot++){
      bfrag bb = *(const bfrag*)(Wo + (size_t)(ot * 16 + lcol) * C + s * 32 + quad * 8);
      acc[ot] = __builtin_amdgcn_mfma_f32_16x16x32_bf16(a, bb, acc[ot], 0, 0, 0);
    }
  }
#pragma unroll
  for (int ot = 0; ot < 8; ot++){
    float bias = Wob[ot * 16 + lcol];
#pragma unroll
    for (int r = 0; r < 4; r++){
      out[(size_t)(m0 + quad * 4 + r) * C + ot * 16 + lcol] = acc[ot][r] + bias;   // fp32 store
    }
  }
}

// ================= host =================

extern "C" void kernel_launch(void* const* d_in, const int* in_sizes, int n_in,
                              void* d_out, int out_size, void* d_ws, size_t ws_size,
                              hipStream_t stream){
  const float* x    = (const float*)d_in[0];
  const int*   eidx = (const int*)d_in[1];
  const float* ew   = (const float*)d_in[2];
  const int*   n_nodes = (const int*)d_in[3];
  const float* Wq_w = (const float*)d_in[4];
  const float* Wq_b = (const float*)d_in[5];
  const float* Wk_w = (const float*)d_in[6];
  const float* Wk_b = (const float*)d_in[7];
  const float* Wo_w = (const float*)d_in[8];
  const float* Wo_b = (const float*)d_in[9];
  float* out = (float*)d_out;                  // fp32 output

  int N = in_sizes[0] / C;
  int E = in_sizes[2];
  int B = in_sizes[3];
  int PG = N / B;
  const int* row = eidx;
  const int* col = eidx + E;

  char* p = (char*)d_ws;
  auto alloc = [&](size_t bytes) -> void* {
    void* r = (void*)p; p += (bytes + 255) & ~(size_t)255; return r;
  };
  unsigned short* cur16 = (unsigned short*)alloc((size_t)N * C * 2);
  unsigned short* curT  = (unsigned short*)alloc((size_t)N * C * 2);
  unsigned short* qs16  = (unsigned short*)alloc((size_t)N * C * 2);
  unsigned short* ksT   = (unsigned short*)alloc((size_t)N * C * 2);
  unsigned short* gcn16 = (unsigned short*)alloc((size_t)N * C * 2);
  unsigned short* acc16 = (unsigned short*)alloc((size_t)N * C * 2);
  float*          accf  = (float*)alloc((size_t)N * C * 4);
  unsigned short* MT    = (unsigned short*)alloc((size_t)B * C * C * 2);
  unsigned short* Wq16  = (unsigned short*)alloc((size_t)C * C * 2);
  unsigned short* Wk16  = (unsigned short*)alloc((size_t)C * C * 2);
  unsigned short* Wo16  = (unsigned short*)alloc((size_t)C * C * 2);
  float*          deg   = (float*)alloc((size_t)N * 4);
  float*          dinv  = (float*)alloc((size_t)N * 4);
  int*            cnt   = (int*)alloc((size_t)N * 4);
  int*            row_ptr = (int*)alloc((size_t)(N + 1) * 4);
  int*            fill  = (int*)alloc((size_t)N * 4);
  int*            bsum  = (int*)alloc(1024);
  int*            bbase = (int*)alloc(1024);
  int*            col_s = (int*)alloc((size_t)E * 4);
  float*          coef_s = (float*)alloc((size_t)E * 4);
  float*          ksum  = (float*)alloc((size_t)B * C * 4);
  float*          vsumA = (float*)alloc((size_t)B * C * 4);
  float*          vsumB = (float*)alloc((size_t)B * C * 4);
  float*          denom = (float*)alloc((size_t)N * 4);

  dim3 b256(256);
  int wblocks = (N / 16 + 3) / 4;   // one wave per 16 nodes, 4 waves/block
  int WW = C * C;
  int nscan = (N + 255) / 256;

  // loop-invariant prep
  k_zero<<<dim3((N + 255) / 256), b256, 0, stream>>>(deg, cnt, N);
  k_zero<<<dim3((B * C + 255) / 256), b256, 0, stream>>>(ksum, (int*)nullptr, B * C);
  k_zero<<<dim3((B * C + 255) / 256), b256, 0, stream>>>(vsumA, (int*)nullptr, B * C);
  k_deg<<<dim3((E + 255) / 256), b256, 0, stream>>>(row, ew, deg, cnt, E);
  k_dinv<<<dim3((N + 255) / 256), b256, 0, stream>>>(deg, dinv, N);
  k_scan1<<<dim3(nscan), b256, 0, stream>>>(cnt, bsum, N);
  k_scan2<<<1, b256, 0, stream>>>(bsum, bbase, nscan);
  k_scan3<<<dim3(nscan), b256, 0, stream>>>(cnt, bbase, row_ptr, fill, N);
  k_fill<<<dim3((E + 255) / 256), b256, 0, stream>>>(row, col, ew, dinv, fill, col_s, coef_s, E);
  k_init<<<dim3((N * C + 255) / 256), b256, 0, stream>>>(x, cur16, accf, N * C);
  k_cast<<<dim3((WW + 255) / 256), b256, 0, stream>>>(Wq_w, Wq16, WW);
  k_cast<<<dim3((WW + 255) / 256), b256, 0, stream>>>(Wk_w, Wk16, WW);
  k_cast<<<dim3((WW + 255) / 256), b256, 0, stream>>>(Wo_w, Wo16, WW);
  k_transpose<<<dim3(N / 64, C / 64), b256, 0, stream>>>(cur16, curT, N);
  k_proj<<<dim3(wblocks), b256, 0, stream>>>(cur16, Wq16, Wq_b, qs16, (float*)nullptr, N, PG, 0);
  k_proj<<<dim3(wblocks), b256, 0, stream>>>(cur16, Wk16, Wk_b, ksT, ksum, N, PG, 1);
  k_denom<<<dim3((N + 3) / 4), b256, 0, stream>>>(qs16, ksum, n_nodes, denom, N, PG);
  k_vsum<<<dim3(B, 8), dim3(C), 0, stream>>>(cur16, vsumA, PG);   // vsum of bf16(x)

  // 4 propagation iterations (vsum ping-pong; phase2 folds next-iter vsum)
  float* vs_cur = vsumA;
  float* vs_nxt = vsumB;
  for (int it = 0; it < 4; it++){
    int last = (it == 3);
    if (!last)
      k_zero<<<dim3((B * C + 255) / 256), b256, 0, stream>>>(vs_nxt, (int*)nullptr, B * C);
    k_M<<<dim3(4, B), b256, 0, stream>>>(ksT, curT, MT, N, PG);
    k_gcn<<<dim3((N + 3) / 4), b256, 0, stream>>>(row_ptr, col_s, coef_s,
                                                  (const unsigned int*)cur16,
                                                  (unsigned int*)gcn16, N);
    k_phase2<<<dim3(wblocks), b256, 0, stream>>>(qs16, MT, vs_cur, denom, gcn16,
                                                 cur16, curT, accf, acc16,
                                                 last ? (float*)nullptr : vs_nxt,
                                                 N, PG, last);
    float* tmp = vs_cur; vs_cur = vs_nxt; vs_nxt = tmp;
  }

  k_final<<<dim3(wblocks), b256, 0, stream>>>(acc16, Wo16, Wo_b, out, N);
}